// Round 6
// baseline (315.717 us; speedup 1.0000x reference)
//
#include <hip/hip_runtime.h>
#include <hip/hip_fp16.h>

#define H 1024
#define E 8
#define TT 8192  // tokens = B*S

typedef __attribute__((ext_vector_type(8))) short bf16x8;
typedef __attribute__((ext_vector_type(4))) float f32x4;

__device__ __forceinline__ unsigned short f2bf(float f) {
  unsigned int u = __float_as_uint(f);
  u += 0x7fffu + ((u >> 16) & 1u);
  return (unsigned short)(u >> 16);
}

// LDS tile addressing: rows of 32 bf16 = 64B = 4 chunks of 16B.
// XOR swizzle chunk' = c ^ ((row>>1)&3): conflict-free writes AND mfma b128 reads (0 conflicts, R3-R5).
__device__ __forceinline__ int swz(int row, int c) {
  return (row << 5) | (((c ^ (row >> 1)) & 3) << 3);
}

// async global->LDS, 16B per lane; LDS dest = wave-uniform base + lane*16 (linear).
__device__ __forceinline__ void gld16(void* lds, const void* g) {
  __builtin_amdgcn_global_load_lds((const __attribute__((address_space(1))) void*)g,
                                   (__attribute__((address_space(3))) void*)lds, 16, 0, 0);
}

__global__ __launch_bounds__(64) void k_init(int* cnt, double* psum) {
  int t = threadIdx.x;
  if (t < E) { cnt[t] = 0; psum[t] = 0.0; }
}

// We [E][H][H] f32 -> wet [E][n][k] bf16
__global__ __launch_bounds__(256) void k_cast_we(const float* __restrict__ we, unsigned short* __restrict__ wet) {
  __shared__ unsigned short tile[32][33];
  int e = blockIdx.z;
  int kb = blockIdx.x << 5, nb = blockIdx.y << 5;
  int t = threadIdx.x;
  int cc = t & 31, rr = t >> 5;
  size_t base = (size_t)e * H * H;
#pragma unroll
  for (int r = 0; r < 4; ++r) {
    int k = kb + rr + (r << 3);
    tile[rr + (r << 3)][cc] = f2bf(we[base + (size_t)k * H + nb + cc]);
  }
  __syncthreads();
#pragma unroll
  for (int r = 0; r < 4; ++r) {
    int n = nb + rr + (r << 3);
    wet[base + (size_t)n * H + kb + cc] = tile[cc][rr + (r << 3)];
  }
}

// w1 [k][n] f32 (scaled by lsc[k]) -> w1h/w1l [n][k] bf16 hi/lo split
__global__ __launch_bounds__(256) void k_cast_w1(const float* __restrict__ w1, const float* __restrict__ lsc,
                                                 unsigned short* __restrict__ w1h, unsigned short* __restrict__ w1l) {
  __shared__ float tile[32][33];
  int kb = blockIdx.x << 5, nb = blockIdx.y << 5;
  int t = threadIdx.x;
  int cc = t & 31, rr = t >> 5;
#pragma unroll
  for (int r = 0; r < 4; ++r) {
    int k = kb + rr + (r << 3);
    tile[rr + (r << 3)][cc] = w1[(size_t)k * H + nb + cc] * lsc[k];
  }
  __syncthreads();
#pragma unroll
  for (int r = 0; r < 4; ++r) {
    int n = nb + rr + (r << 3);
    float v = tile[cc][rr + (r << 3)];
    unsigned short h = f2bf(v);
    float hv = __uint_as_float((unsigned)h << 16);
    unsigned short l = f2bf(v - hv);
    w1h[(size_t)n * H + kb + cc] = h;
    w1l[(size_t)n * H + kb + cc] = l;
  }
}

// part[64][H]: block bk sums lbi[k]*w1[k][n] over its 16 k's (deterministic)
__global__ __launch_bounds__(256) void k_b1a(const float* __restrict__ w1, const float* __restrict__ lbi,
                                             float* __restrict__ part) {
  int bk = blockIdx.x, t = threadIdx.x;
  float a0 = 0, a1 = 0, a2 = 0, a3 = 0;
  for (int kk = 0; kk < 16; ++kk) {
    int k = (bk << 4) + kk;
    float lb = lbi[k];
    const float* row = &w1[(size_t)k * H];
    a0 = fmaf(lb, row[t], a0);
    a1 = fmaf(lb, row[t + 256], a1);
    a2 = fmaf(lb, row[t + 512], a2);
    a3 = fmaf(lb, row[t + 768], a3);
  }
  part[bk * H + t] = a0;
  part[bk * H + t + 256] = a1;
  part[bk * H + t + 512] = a2;
  part[bk * H + t + 768] = a3;
}

__global__ __launch_bounds__(256) void k_b1b(const float* __restrict__ part, const float* __restrict__ b1,
                                             float* __restrict__ b1eff) {
  int n = (blockIdx.x << 8) + threadIdx.x;
  float s = b1[n];
  for (int j = 0; j < 64; ++j) s += part[j * H + n];
  b1eff[n] = s;
}

// LN stats + THREE casts: xb = f2bf(x) (experts); zh/zl = trunc hi/lo split of z=(x-m)*rstd (router A).
__global__ __launch_bounds__(256) void k_stats(const float* __restrict__ x, unsigned short* __restrict__ xb,
                                               unsigned short* __restrict__ zh, unsigned short* __restrict__ zl) {
  int tok = blockIdx.x, t = threadIdx.x;
  const float4 v = *reinterpret_cast<const float4*>(&x[(size_t)tok * H + (t << 2)]);
  float s = v.x + v.y + v.z + v.w;
  float ss = v.x * v.x + v.y * v.y + v.z * v.z + v.w * v.w;
#pragma unroll
  for (int off = 32; off; off >>= 1) { s += __shfl_down(s, off); ss += __shfl_down(ss, off); }
  __shared__ float red[4][2];
  int lane = t & 63, wv = t >> 6;
  if (lane == 0) { red[wv][0] = s; red[wv][1] = ss; }
  __syncthreads();
  float fs = red[0][0] + red[1][0] + red[2][0] + red[3][0];
  float fss = red[0][1] + red[1][1] + red[2][1] + red[3][1];
  float mean = fs * (1.0f / H);
  float var = fss * (1.0f / H) - mean * mean;
  float rstd = rsqrtf(var + 1e-5f);
  float mb = -mean * rstd;
  size_t base = (size_t)tok * H + (t << 2);
  ushort4 ob;
  ob.x = f2bf(v.x); ob.y = f2bf(v.y); ob.z = f2bf(v.z); ob.w = f2bf(v.w);
  *reinterpret_cast<ushort4*>(&xb[base]) = ob;
  float zz[4];
  zz[0] = fmaf(v.x, rstd, mb); zz[1] = fmaf(v.y, rstd, mb);
  zz[2] = fmaf(v.z, rstd, mb); zz[3] = fmaf(v.w, rstd, mb);
  ushort4 oh, ol;
  unsigned u0 = __float_as_uint(zz[0]), u1 = __float_as_uint(zz[1]);
  unsigned u2 = __float_as_uint(zz[2]), u3 = __float_as_uint(zz[3]);
  oh.x = (unsigned short)(u0 >> 16); oh.y = (unsigned short)(u1 >> 16);
  oh.z = (unsigned short)(u2 >> 16); oh.w = (unsigned short)(u3 >> 16);
  float l0 = zz[0] - __uint_as_float(u0 & 0xffff0000u);
  float l1 = zz[1] - __uint_as_float(u1 & 0xffff0000u);
  float l2 = zz[2] - __uint_as_float(u2 & 0xffff0000u);
  float l3 = zz[3] - __uint_as_float(u3 & 0xffff0000u);
  ol.x = (unsigned short)(__float_as_uint(l0) >> 16); ol.y = (unsigned short)(__float_as_uint(l1) >> 16);
  ol.z = (unsigned short)(__float_as_uint(l2) >> 16); ol.w = (unsigned short)(__float_as_uint(l3) >> 16);
  *reinterpret_cast<ushort4*>(&zh[base]) = oh;
  *reinterpret_cast<ushort4*>(&zl[base]) = ol;
}

// Router GEMM: hmid-tile = z @ (lsc*w1), 3-pass hi/lo bf16 MFMA.
// A-frags: direct per-lane int4 loads from zh/zl (register double-buffer, no LDS).
// B (w1h+w1l): gload_lds 3-buffer, counted vmcnt(12), ONE barrier per K-step.
// XCD chunk bm-major (w1 streamed once per XCD; zh/zl slice ~L2-resident).
__global__ __launch_bounds__(256) void k_router_mfma(
    const unsigned short* __restrict__ zh, const unsigned short* __restrict__ zl,
    const unsigned short* __restrict__ w1h,  // w1l = w1h + 1048576 shorts (adjacent in ws)
    const float* __restrict__ b1eff, const float* __restrict__ w2, float* __restrict__ plog) {
  __shared__ __align__(16) short Bt[3][8192];  // 3 x (256 rows x 32): rows 0-127 hi, 128-255 lo
  int t = threadIdx.x;
  int d = blockIdx.x;
  int l = ((d & 7) << 6) + (d >> 3);  // XCD owns contiguous 64-block chunk
  int bm = (l >> 3) << 7;             // 8 token-tiles per XCD
  int bnb = l & 7, bn = bnb << 7;     // n-panel fastest
  int w = t >> 6, lane = t & 63;
  int l15 = lane & 15, lgp = lane >> 4;
  int wr = (w >> 1) << 6, wc = (w & 1) << 6;
  // B staging: 4 slots/lane, pre-swizzled source offsets (shorts rel. w1h)
  int sl = (w << 8) + lane;
  int bo[4];
#pragma unroll
  for (int q = 0; q < 4; ++q) {
    int s = sl + (q << 6);
    int r = s >> 2, cg = (s & 3) ^ ((r >> 1) & 3);
    bo[q] = ((r < 128) ? (bn + r) * H : 1048576 + (bn + r - 128) * H) + (cg << 3);
  }
  int dB = w << 11;  // wave-uniform LDS short-offset (+512 per q)
  // A: per-lane fragment offsets (shorts)
  int zo[4];
#pragma unroll
  for (int i = 0; i < 4; ++i) zo[i] = (bm + wr + (i << 4) + l15) * H + (lgp << 3);
  f32x4 acc[4][4];
#pragma unroll
  for (int i = 0; i < 4; ++i)
#pragma unroll
    for (int j = 0; j < 4; ++j) acc[i][j] = f32x4{0.f, 0.f, 0.f, 0.f};
  bf16x8 ah[2][4], al[2][4];
  // prologue: stage B(0),B(1); load A(0)
#pragma unroll
  for (int q = 0; q < 4; ++q) gld16(&Bt[0][dB + (q << 9)], w1h + bo[q]);
#pragma unroll
  for (int q = 0; q < 4; ++q) gld16(&Bt[1][dB + (q << 9)], w1h + bo[q] + 32);
#pragma unroll
  for (int i = 0; i < 4; ++i) {
    ah[0][i] = *(const bf16x8*)(zh + zo[i]);
    al[0][i] = *(const bf16x8*)(zl + zo[i]);
  }
#pragma unroll
  for (int kt = 0; kt < 32; ++kt) {
    const int cur = kt & 1, nxt = cur ^ 1;
    if (kt < 31) {  // A(t+1) register prefetch (issued before the wait -> stays in flight)
      const int ko = (kt + 1) << 5;
#pragma unroll
      for (int i = 0; i < 4; ++i) {
        ah[nxt][i] = *(const bf16x8*)(zh + zo[i] + ko);
        al[nxt][i] = *(const bf16x8*)(zl + zo[i] + ko);
      }
    }
    if (kt <= 30) {
      asm volatile("s_waitcnt vmcnt(12)" ::: "memory");  // drains B(t),A(t); keeps B(t+1)+A(t+1)
    } else {
      asm volatile("s_waitcnt vmcnt(0)" ::: "memory");
    }
    __builtin_amdgcn_sched_barrier(0);
    __builtin_amdgcn_s_barrier();
    __builtin_amdgcn_sched_barrier(0);
    if (kt < 30) {  // stage B(t+2) into buf freed by barrier (all waves done reading it at t-1)
      const int bnxt = (kt + 2) % 3, ko = (kt + 2) << 5;
#pragma unroll
      for (int q = 0; q < 4; ++q) gld16(&Bt[bnxt][dB + (q << 9)], w1h + bo[q] + ko);
    }
    const int bb = kt % 3;
#pragma unroll
    for (int j = 0; j < 4; ++j) {
      bf16x8 bh = *(const bf16x8*)&Bt[bb][swz(wc + (j << 4) + l15, lgp)];
      bf16x8 bl = *(const bf16x8*)&Bt[bb][swz(128 + wc + (j << 4) + l15, lgp)];
#pragma unroll
      for (int i = 0; i < 4; ++i) {
        acc[i][j] = __builtin_amdgcn_mfma_f32_16x16x32_bf16(ah[cur][i], bh, acc[i][j], 0, 0, 0);
        acc[i][j] = __builtin_amdgcn_mfma_f32_16x16x32_bf16(ah[cur][i], bl, acc[i][j], 0, 0, 0);
        acc[i][j] = __builtin_amdgcn_mfma_f32_16x16x32_bf16(al[cur][i], bh, acc[i][j], 0, 0, 0);
      }
    }
  }
  // epilogue: bias + relu, then partial logits over this wave's 64 columns
  float w2r[4][8], b1r[4];
#pragma unroll
  for (int j = 0; j < 4; ++j) {
    int col = bn + wc + (j << 4) + l15;
    float4 p0 = *(const float4*)&w2[(size_t)col * E];
    float4 p1 = *(const float4*)&w2[(size_t)col * E + 4];
    w2r[j][0] = p0.x; w2r[j][1] = p0.y; w2r[j][2] = p0.z; w2r[j][3] = p0.w;
    w2r[j][4] = p1.x; w2r[j][5] = p1.y; w2r[j][6] = p1.z; w2r[j][7] = p1.w;
    b1r[j] = b1eff[col];
  }
#pragma unroll
  for (int i = 0; i < 4; ++i)
#pragma unroll
    for (int j = 0; j < 4; ++j)
#pragma unroll
      for (int r = 0; r < 4; ++r) acc[i][j][r] = fmaxf(acc[i][j][r] + b1r[j], 0.f);
  int wh = wc >> 6;
  size_t pbase = ((size_t)(bnb * 2 + wh) * TT + bm) * E;
#pragma unroll
  for (int e = 0; e < E; ++e) {
    float se[4][4];
#pragma unroll
    for (int i = 0; i < 4; ++i)
#pragma unroll
      for (int r = 0; r < 4; ++r)
        se[i][r] = acc[i][0][r] * w2r[0][e] + acc[i][1][r] * w2r[1][e] +
                   acc[i][2][r] * w2r[2][e] + acc[i][3][r] * w2r[3][e];
#pragma unroll
    for (int off = 1; off < 16; off <<= 1)
#pragma unroll
      for (int i = 0; i < 4; ++i)
#pragma unroll
        for (int r = 0; r < 4; ++r) se[i][r] += __shfl_xor(se[i][r], off);
    if (l15 == 0) {
#pragma unroll
      for (int i = 0; i < 4; ++i)
#pragma unroll
        for (int r = 0; r < 4; ++r) {
          int row = wr + (i << 4) + (lgp << 2) + r;
          plog[pbase + (size_t)row * E + e] = se[i][r];
        }
    }
  }
}

// thread-per-token: sum 16 logit partials + b2 -> softmax -> top2 -> renorm; wave-aggregated lists + psum
__global__ __launch_bounds__(256) void k_top(const float* __restrict__ plog, const float* __restrict__ b2,
                                             int* __restrict__ topE, float* __restrict__ topW,
                                             int* __restrict__ listIdx, float* __restrict__ listW,
                                             int* __restrict__ cnt, double* __restrict__ psum) {
  int t = threadIdx.x, lane = t & 63;
  int tok = (blockIdx.x << 8) + t;
  float lg[E], p[E];
  float4 ba = *reinterpret_cast<const float4*>(b2);
  float4 bb = *reinterpret_cast<const float4*>(b2 + 4);
  lg[0] = ba.x; lg[1] = ba.y; lg[2] = ba.z; lg[3] = ba.w;
  lg[4] = bb.x; lg[5] = bb.y; lg[6] = bb.z; lg[7] = bb.w;
#pragma unroll
  for (int nb = 0; nb < 16; ++nb) {
    const float* pp = &plog[((size_t)nb * TT + tok) * E];
    float4 q0 = *reinterpret_cast<const float4*>(pp);
    float4 q1 = *reinterpret_cast<const float4*>(pp + 4);
    lg[0] += q0.x; lg[1] += q0.y; lg[2] += q0.z; lg[3] += q0.w;
    lg[4] += q1.x; lg[5] += q1.y; lg[6] += q1.z; lg[7] += q1.w;
  }
  float m = lg[0];
#pragma unroll
  for (int e = 1; e < E; ++e) m = fmaxf(m, lg[e]);
  float s = 0.f;
#pragma unroll
  for (int e = 0; e < E; ++e) { p[e] = __expf(lg[e] - m); s += p[e]; }
  float inv = 1.f / s;
#pragma unroll
  for (int e = 0; e < E; ++e) p[e] *= inv;
  {
    float ps[E];
#pragma unroll
    for (int e = 0; e < E; ++e) ps[e] = p[e];
#pragma unroll
    for (int off = 1; off < 64; off <<= 1)
#pragma unroll
      for (int e = 0; e < E; ++e) ps[e] += __shfl_xor(ps[e], off);
    if (lane == 0)
#pragma unroll
      for (int e = 0; e < E; ++e) atomicAdd(&psum[e], (double)ps[e]);
  }
  int e0 = 0;
#pragma unroll
  for (int e = 1; e < E; ++e) if (p[e] > p[e0]) e0 = e;  // strict >: first max (jax tie order)
  int e1 = (e0 == 0) ? 1 : 0;
#pragma unroll
  for (int e = 0; e < E; ++e) if (e != e0 && p[e] > p[e1]) e1 = e;
  float rsw = 1.f / (p[e0] + p[e1]);
  float w0 = p[e0] * rsw, w1v = p[e1] * rsw;
  topE[tok << 1] = e0; topE[(tok << 1) + 1] = e1;
  topW[tok << 1] = w0; topW[(tok << 1) + 1] = w1v;
  unsigned long long lt = (1ull << lane) - 1ull;
#pragma unroll
  for (int e = 0; e < E; ++e) {
    unsigned long long m0 = __ballot(e0 == e);
    unsigned long long m1 = __ballot(e1 == e);
    int n0 = __popcll(m0), total = n0 + __popcll(m1);
    if (total == 0) continue;  // wave-uniform
    int leader = __ffsll(m0 | m1) - 1;
    int base = 0;
    if (lane == leader) base = atomicAdd(&cnt[e], total);
    base = __shfl(base, leader);
    if (e0 == e) {
      int pos = e * TT + base + __popcll(m0 & lt);
      listIdx[pos] = (tok << 1); listW[pos] = w0;
    }
    if (e1 == e) {
      int pos = e * TT + base + n0 + __popcll(m1 & lt);
      listIdx[pos] = (tok << 1) | 1; listW[pos] = w1v;
    }
  }
}

// grouped bf16 MFMA GEMM: gathered token rows @ We[e]^T.
// A-frags: direct per-lane int4 gathers from xb (register double-buffer, no LDS).
// B: gload_lds 3-buffer, counted vmcnt(6), ONE barrier per K-step.
// XCD chunk: expert-per-XCD, by-fastest (We[e] slice L2-resident).
__global__ __launch_bounds__(256) void k_expert_gemm(const unsigned short* __restrict__ xb,
                                                     const unsigned short* __restrict__ wet,
                                                     const int* __restrict__ listIdx, const float* __restrict__ listW,
                                                     const int* __restrict__ cnt, unsigned short* __restrict__ ys) {
  int d = blockIdx.x;
  int l = ((d & 7) << 9) + (d >> 3);  // XCD owns one expert's 512 blocks
  int e = l >> 9;
  int lx = l & 511;
  int bx = lx >> 3, by = lx & 7;      // by fastest: B panel reused in L2
  int c = cnt[e];
  int r0 = bx << 7;
  if (r0 >= c) return;
  int n0 = by << 7;
  __shared__ __align__(16) short B[3][4096];
  __shared__ int gi[128];
  __shared__ float gw[128];
  int t = threadIdx.x;
  if (t < 128) {
    int rr = r0 + t;
    gi[t] = (rr < c) ? listIdx[e * TT + rr] : -1;
    gw[t] = (rr < c) ? listW[e * TT + rr] : 0.f;
  }
  __syncthreads();
  int w = t >> 6, lane = t & 63;
  int l15 = lane & 15, lgp = lane >> 4;
  int wr = (w >> 1) << 6, wc = (w & 1) << 6;
  // B staging: 2 slots/lane, pre-swizzled source offsets (shorts rel. wet[e])
  int sl = (w << 7) + lane;
  int ebase = e << 20;  // e*H*H shorts
  int bo[2];
#pragma unroll
  for (int q = 0; q < 2; ++q) {
    int s = sl + (q << 6);
    int r = s >> 2, cg = (s & 3) ^ ((r >> 1) & 3);
    bo[q] = ebase + (n0 + r) * H + (cg << 3);
  }
  int dB = w << 10;  // wave-uniform LDS short-offset (+512 per q)
  // A: per-lane gathered fragment offsets (shorts)
  int ao[4];
#pragma unroll
  for (int i = 0; i < 4; ++i) {
    int pk = gi[wr + (i << 4) + l15];
    int tok = (pk < 0) ? 0 : (pk >> 1);
    ao[i] = tok * H + (lgp << 3);
  }
  f32x4 acc[4][4];
#pragma unroll
  for (int i = 0; i < 4; ++i)
#pragma unroll
    for (int j = 0; j < 4; ++j) acc[i][j] = f32x4{0.f, 0.f, 0.f, 0.f};
  bf16x8 a[2][4];
  // prologue: stage B(0),B(1); load A(0)
#pragma unroll
  for (int q = 0; q < 2; ++q) gld16(&B[0][dB + (q << 9)], wet + bo[q]);
#pragma unroll
  for (int q = 0; q < 2; ++q) gld16(&B[1][dB + (q << 9)], wet + bo[q] + 32);
#pragma unroll
  for (int i = 0; i < 4; ++i) a[0][i] = *(const bf16x8*)(xb + ao[i]);
#pragma unroll
  for (int kt = 0; kt < 32; ++kt) {
    const int cur = kt & 1, nxt = cur ^ 1;
    if (kt < 31) {
      const int ko = (kt + 1) << 5;
#pragma unroll
      for (int i = 0; i < 4; ++i) a[nxt][i] = *(const bf16x8*)(xb + ao[i] + ko);
    }
    if (kt <= 30) {
      asm volatile("s_waitcnt vmcnt(6)" ::: "memory");  // drains B(t),A(t); keeps B(t+1)+A(t+1)
    } else {
      asm volatile("s_waitcnt vmcnt(0)" ::: "memory");
    }
    __builtin_amdgcn_sched_barrier(0);
    __builtin_amdgcn_s_barrier();
    __builtin_amdgcn_sched_barrier(0);
    if (kt < 30) {
      const int bnxt = (kt + 2) % 3, ko = (kt + 2) << 5;
#pragma unroll
      for (int q = 0; q < 2; ++q) gld16(&B[bnxt][dB + (q << 9)], wet + bo[q] + ko);
    }
    const int bb = kt % 3;
#pragma unroll
    for (int j = 0; j < 4; ++j) {
      bf16x8 bq = *(const bf16x8*)&B[bb][swz(wc + (j << 4) + l15, lgp)];
#pragma unroll
      for (int i = 0; i < 4; ++i)
        acc[i][j] = __builtin_amdgcn_mfma_f32_16x16x32_bf16(a[cur][i], bq, acc[i][j], 0, 0, 0);
    }
  }
#pragma unroll
  for (int i = 0; i < 4; ++i) {
#pragma unroll
    for (int r = 0; r < 4; ++r) {
      int row = wr + (i << 4) + (lgp << 2) + r;  // C/D: col=lane&15, row=(lane>>4)*4+reg
      int pk = gi[row];
      if (pk < 0) continue;
      int tok = pk >> 1, slot = pk & 1;
      float wgt = gw[row];
      size_t ob = ((size_t)slot * TT + tok) * H + n0 + wc + l15;
#pragma unroll
      for (int j = 0; j < 4; ++j) ys[ob + (j << 4)] = __half_as_ushort(__float2half(wgt * acc[i][j][r]));
    }
  }
}

// out = y_slot0 + y_slot1 + w0*be[e0] + w1*be[e1]
__global__ __launch_bounds__(256) void k_combine(const unsigned short* __restrict__ ys, const int* __restrict__ topE,
                                                 const float* __restrict__ topW, const float* __restrict__ be,
                                                 float* __restrict__ out) {
  int tok = blockIdx.x, t = threadIdx.x;
  int e0 = topE[tok << 1], e1 = topE[(tok << 1) + 1];
  float w0 = topW[tok << 1], w1v = topW[(tok << 1) + 1];
  int h = t << 2;
  size_t base = (size_t)tok * H + h;
  ushort4 a = *reinterpret_cast<const ushort4*>(&ys[base]);
  ushort4 b = *reinterpret_cast<const ushort4*>(&ys[(size_t)TT * H + base]);
  float4 b0 = *reinterpret_cast<const float4*>(&be[e0 * H + h]);
  float4 b1v = *reinterpret_cast<const float4*>(&be[e1 * H + h]);
  float4 o;
  o.x = __half2float(__ushort_as_half(a.x)) + __half2float(__ushort_as_half(b.x)) + w0 * b0.x + w1v * b1v.x;
  o.y = __half2float(__ushort_as_half(a.y)) + __half2float(__ushort_as_half(b.y)) + w0 * b0.y + w1v * b1v.y;
  o.z = __half2float(__ushort_as_half(a.z)) + __half2float(__ushort_as_half(b.z)) + w0 * b0.z + w1v * b1v.z;
  o.w = __half2float(__ushort_as_half(a.w)) + __half2float(__ushort_as_half(b.w)) + w0 * b0.w + w1v * b1v.w;
  *reinterpret_cast<float4*>(&out[base]) = o;
}

__global__ __launch_bounds__(64) void k_aux(const double* __restrict__ psum, float* __restrict__ outAux) {
  if (threadIdx.x == 0) {
    double a = 0.0;
    for (int e = 0; e < E; ++e) {
      double mp = psum[e] / (double)TT;
      a += mp * log(mp * (double)E + 1e-9);
    }
    outAux[0] = (float)a;
  }
}

extern "C" void kernel_launch(void* const* d_in, const int* in_sizes, int n_in, void* d_out, int out_size, void* d_ws,
                              size_t ws_size, hipStream_t stream) {
  const float* x = (const float*)d_in[0];
  const float* lsc = (const float*)d_in[1];
  const float* lbi = (const float*)d_in[2];
  const float* w1 = (const float*)d_in[3];
  const float* b1 = (const float*)d_in[4];
  const float* w2 = (const float*)d_in[5];
  const float* b2 = (const float*)d_in[6];
  const float* we = (const float*)d_in[7];
  const float* be = (const float*)d_in[8];
  float* out = (float*)d_out;
  char* ws = (char*)d_ws;

  // ws timeline (peak 66 MB):
  // [0,1M): small; [2,18M): xb; [18,34M): zh -> wet (after router); [34,50M): zl -> ys lo half;
  // [50,54M): w1h+w1l (dead after router); [54,58M): plog (dead after k_top); ys = [34,66M).
  char* p = ws;
  int* topE = (int*)p; p += TT * 2 * 4;
  float* topW = (float*)p; p += TT * 2 * 4;
  int* listIdx = (int*)p; p += E * TT * 4;
  float* listW = (float*)p; p += E * TT * 4;
  int* cnt = (int*)p; p += 256;
  double* psum = (double*)p; p += 2048;
  float* b1eff = (float*)p; p += H * 4;
  float* part = (float*)p; p += 64 * H * 4;
  unsigned short* xb = (unsigned short*)(ws + (2ull << 20));
  unsigned short* zh = (unsigned short*)(ws + (18ull << 20));
  unsigned short* zl = (unsigned short*)(ws + (34ull << 20));
  unsigned short* w1h = (unsigned short*)(ws + (50ull << 20));
  unsigned short* w1l = (unsigned short*)(ws + (52ull << 20));
  float* plog = (float*)(ws + (54ull << 20));
  unsigned short* wet = (unsigned short*)(ws + (18ull << 20));  // overlays zh (after router)
  unsigned short* ys = (unsigned short*)(ws + (34ull << 20));   // overlays zl/w1/plog (after k_top)

  k_init<<<1, 64, 0, stream>>>(cnt, psum);
  k_cast_w1<<<dim3(32, 32), 256, 0, stream>>>(w1, lsc, w1h, w1l);
  k_b1a<<<64, 256, 0, stream>>>(w1, lbi, part);
  k_b1b<<<4, 256, 0, stream>>>(part, b1, b1eff);
  k_stats<<<TT, 256, 0, stream>>>(x, xb, zh, zl);
  k_router_mfma<<<512, 256, 0, stream>>>(zh, zl, w1h, b1eff, w2, plog);
  k_top<<<TT / 256, 256, 0, stream>>>(plog, b2, topE, topW, listIdx, listW, cnt, psum);
  k_cast_we<<<dim3(32, 32, E), 256, 0, stream>>>(we, wet);
  k_expert_gemm<<<4096, 256, 0, stream>>>(xb, wet, listIdx, listW, cnt, ys);
  k_combine<<<TT, 256, 0, stream>>>(ys, topE, topW, be, out);
  k_aux<<<1, 64, 0, stream>>>(psum, out + (size_t)TT * H);
}

// Round 7
// 252.082 us; speedup vs baseline: 1.2524x; 1.2524x over previous
//
#include <hip/hip_runtime.h>
#include <hip/hip_fp16.h>

#define H 1024
#define E 8
#define TT 8192  // tokens = B*S

typedef __attribute__((ext_vector_type(8))) short bf16x8;
typedef __attribute__((ext_vector_type(4))) float f32x4;

__device__ __forceinline__ unsigned short f2bf(float f) {
  unsigned int u = __float_as_uint(f);
  u += 0x7fffu + ((u >> 16) & 1u);
  return (unsigned short)(u >> 16);
}

// LDS tile addressing: rows of 32 bf16 = 64B = 4 chunks of 16B.
// XOR swizzle chunk' = c ^ ((row>>1)&3): conflict-free writes AND mfma b128 reads (0 conflicts, R3-R6).
__device__ __forceinline__ int swz(int row, int c) {
  return (row << 5) | (((c ^ (row >> 1)) & 3) << 3);
}

// async global->LDS, 16B per lane; LDS dest = wave-uniform base + lane*16 (linear).
__device__ __forceinline__ void gld16(void* lds, const void* g) {
  __builtin_amdgcn_global_load_lds((const __attribute__((address_space(1))) void*)g,
                                   (__attribute__((address_space(3))) void*)lds, 16, 0, 0);
}

__global__ __launch_bounds__(64) void k_init(int* cnt, double* psum) {
  int t = threadIdx.x;
  if (t < E) { cnt[t] = 0; psum[t] = 0.0; }
}

// We [E][H][H] f32 -> wet [E][n][k] bf16
__global__ __launch_bounds__(256) void k_cast_we(const float* __restrict__ we, unsigned short* __restrict__ wet) {
  __shared__ unsigned short tile[32][33];
  int e = blockIdx.z;
  int kb = blockIdx.x << 5, nb = blockIdx.y << 5;
  int t = threadIdx.x;
  int cc = t & 31, rr = t >> 5;
  size_t base = (size_t)e * H * H;
#pragma unroll
  for (int r = 0; r < 4; ++r) {
    int k = kb + rr + (r << 3);
    tile[rr + (r << 3)][cc] = f2bf(we[base + (size_t)k * H + nb + cc]);
  }
  __syncthreads();
#pragma unroll
  for (int r = 0; r < 4; ++r) {
    int n = nb + rr + (r << 3);
    wet[base + (size_t)n * H + kb + cc] = tile[cc][rr + (r << 3)];
  }
}

// w1 [k][n] f32 (scaled by lsc[k]) -> w1h/w1l [n][k] bf16 hi/lo split
__global__ __launch_bounds__(256) void k_cast_w1(const float* __restrict__ w1, const float* __restrict__ lsc,
                                                 unsigned short* __restrict__ w1h, unsigned short* __restrict__ w1l) {
  __shared__ float tile[32][33];
  int kb = blockIdx.x << 5, nb = blockIdx.y << 5;
  int t = threadIdx.x;
  int cc = t & 31, rr = t >> 5;
#pragma unroll
  for (int r = 0; r < 4; ++r) {
    int k = kb + rr + (r << 3);
    tile[rr + (r << 3)][cc] = w1[(size_t)k * H + nb + cc] * lsc[k];
  }
  __syncthreads();
#pragma unroll
  for (int r = 0; r < 4; ++r) {
    int n = nb + rr + (r << 3);
    float v = tile[cc][rr + (r << 3)];
    unsigned short h = f2bf(v);
    float hv = __uint_as_float((unsigned)h << 16);
    unsigned short l = f2bf(v - hv);
    w1h[(size_t)n * H + kb + cc] = h;
    w1l[(size_t)n * H + kb + cc] = l;
  }
}

// part[64][H]: block bk sums lbi[k]*w1[k][n] over its 16 k's (deterministic)
__global__ __launch_bounds__(256) void k_b1a(const float* __restrict__ w1, const float* __restrict__ lbi,
                                             float* __restrict__ part) {
  int bk = blockIdx.x, t = threadIdx.x;
  float a0 = 0, a1 = 0, a2 = 0, a3 = 0;
  for (int kk = 0; kk < 16; ++kk) {
    int k = (bk << 4) + kk;
    float lb = lbi[k];
    const float* row = &w1[(size_t)k * H];
    a0 = fmaf(lb, row[t], a0);
    a1 = fmaf(lb, row[t + 256], a1);
    a2 = fmaf(lb, row[t + 512], a2);
    a3 = fmaf(lb, row[t + 768], a3);
  }
  part[bk * H + t] = a0;
  part[bk * H + t + 256] = a1;
  part[bk * H + t + 512] = a2;
  part[bk * H + t + 768] = a3;
}

__global__ __launch_bounds__(256) void k_b1b(const float* __restrict__ part, const float* __restrict__ b1,
                                             float* __restrict__ b1eff) {
  int n = (blockIdx.x << 8) + threadIdx.x;
  float s = b1[n];
  for (int j = 0; j < 64; ++j) s += part[j * H + n];
  b1eff[n] = s;
}

// LN stats + THREE casts: xb = f2bf(x) (experts); zh/zl = trunc hi/lo split of z=(x-m)*rstd (router A).
__global__ __launch_bounds__(256) void k_stats(const float* __restrict__ x, unsigned short* __restrict__ xb,
                                               unsigned short* __restrict__ zh, unsigned short* __restrict__ zl) {
  int tok = blockIdx.x, t = threadIdx.x;
  const float4 v = *reinterpret_cast<const float4*>(&x[(size_t)tok * H + (t << 2)]);
  float s = v.x + v.y + v.z + v.w;
  float ss = v.x * v.x + v.y * v.y + v.z * v.z + v.w * v.w;
#pragma unroll
  for (int off = 32; off; off >>= 1) { s += __shfl_down(s, off); ss += __shfl_down(ss, off); }
  __shared__ float red[4][2];
  int lane = t & 63, wv = t >> 6;
  if (lane == 0) { red[wv][0] = s; red[wv][1] = ss; }
  __syncthreads();
  float fs = red[0][0] + red[1][0] + red[2][0] + red[3][0];
  float fss = red[0][1] + red[1][1] + red[2][1] + red[3][1];
  float mean = fs * (1.0f / H);
  float var = fss * (1.0f / H) - mean * mean;
  float rstd = rsqrtf(var + 1e-5f);
  float mb = -mean * rstd;
  size_t base = (size_t)tok * H + (t << 2);
  ushort4 ob;
  ob.x = f2bf(v.x); ob.y = f2bf(v.y); ob.z = f2bf(v.z); ob.w = f2bf(v.w);
  *reinterpret_cast<ushort4*>(&xb[base]) = ob;
  float zz[4];
  zz[0] = fmaf(v.x, rstd, mb); zz[1] = fmaf(v.y, rstd, mb);
  zz[2] = fmaf(v.z, rstd, mb); zz[3] = fmaf(v.w, rstd, mb);
  ushort4 oh, ol;
  unsigned u0 = __float_as_uint(zz[0]), u1 = __float_as_uint(zz[1]);
  unsigned u2 = __float_as_uint(zz[2]), u3 = __float_as_uint(zz[3]);
  oh.x = (unsigned short)(u0 >> 16); oh.y = (unsigned short)(u1 >> 16);
  oh.z = (unsigned short)(u2 >> 16); oh.w = (unsigned short)(u3 >> 16);
  float l0 = zz[0] - __uint_as_float(u0 & 0xffff0000u);
  float l1 = zz[1] - __uint_as_float(u1 & 0xffff0000u);
  float l2 = zz[2] - __uint_as_float(u2 & 0xffff0000u);
  float l3 = zz[3] - __uint_as_float(u3 & 0xffff0000u);
  ol.x = (unsigned short)(__float_as_uint(l0) >> 16); ol.y = (unsigned short)(__float_as_uint(l1) >> 16);
  ol.z = (unsigned short)(__float_as_uint(l2) >> 16); ol.w = (unsigned short)(__float_as_uint(l3) >> 16);
  *reinterpret_cast<ushort4*>(&zh[base]) = oh;
  *reinterpret_cast<ushort4*>(&zl[base]) = ol;
}

// Router GEMM: hmid-tile = z @ (lsc*w1), 3-pass hi/lo bf16 MFMA.
// A: register ring depth 3, prefetch DISTANCE 2 (covers load latency), fully unrolled (static idx).
// B (w1h+w1l): gld16 3-buffer, counted vmcnt(20) (keeps A(t+1),A(t+2),B(t+1) in flight), 1 barrier/step.
__global__ __launch_bounds__(256) void k_router_mfma(
    const unsigned short* __restrict__ zh, const unsigned short* __restrict__ zl,
    const unsigned short* __restrict__ w1h,  // w1l = w1h + 1048576 shorts (adjacent in ws)
    const float* __restrict__ b1eff, const float* __restrict__ w2, float* __restrict__ plog) {
  __shared__ __align__(16) short Bt[3][8192];  // 3 x (256 rows x 32): rows 0-127 hi, 128-255 lo
  int t = threadIdx.x;
  int d = blockIdx.x;
  int l = ((d & 7) << 6) + (d >> 3);  // XCD owns contiguous 64-block chunk (bijective, 512 blocks)
  int bm = (l >> 3) << 7;
  int bnb = l & 7, bn = bnb << 7;
  int w = t >> 6, lane = t & 63;
  int l15 = lane & 15, lgp = lane >> 4;
  int wr = (w >> 1) << 6, wc = (w & 1) << 6;
  // B staging: 4 slots/lane, pre-swizzled source offsets (shorts rel. w1h)
  int sl = (w << 8) + lane;
  int bo[4];
#pragma unroll
  for (int q = 0; q < 4; ++q) {
    int s = sl + (q << 6);
    int r = s >> 2, cg = (s & 3) ^ ((r >> 1) & 3);
    bo[q] = ((r < 128) ? (bn + r) * H : 1048576 + (bn + r - 128) * H) + (cg << 3);
  }
  int dB = w << 11;
  // A: per-lane fragment offsets (shorts)
  int zo[4];
#pragma unroll
  for (int i = 0; i < 4; ++i) zo[i] = (bm + wr + (i << 4) + l15) * H + (lgp << 3);
  f32x4 acc[4][4];
#pragma unroll
  for (int i = 0; i < 4; ++i)
#pragma unroll
    for (int j = 0; j < 4; ++j) acc[i][j] = f32x4{0.f, 0.f, 0.f, 0.f};
  bf16x8 ah[3][4], al[3][4];
  // prologue: stage B(0),B(1); load A(0),A(1)
#pragma unroll
  for (int q = 0; q < 4; ++q) gld16(&Bt[0][dB + (q << 9)], w1h + bo[q]);
#pragma unroll
  for (int q = 0; q < 4; ++q) gld16(&Bt[1][dB + (q << 9)], w1h + bo[q] + 32);
#pragma unroll
  for (int i = 0; i < 4; ++i) {
    ah[0][i] = *(const bf16x8*)(zh + zo[i]);
    al[0][i] = *(const bf16x8*)(zl + zo[i]);
    ah[1][i] = *(const bf16x8*)(zh + zo[i] + 32);
    al[1][i] = *(const bf16x8*)(zl + zo[i] + 32);
  }
#pragma unroll
  for (int kt = 0; kt < 32; ++kt) {
    const int cur = kt % 3;
    if (kt <= 29) {  // A(t+2) register prefetch, distance 2
      const int slot = (kt + 2) % 3, ko = (kt + 2) << 5;
#pragma unroll
      for (int i = 0; i < 4; ++i) {
        ah[slot][i] = *(const bf16x8*)(zh + zo[i] + ko);
        al[slot][i] = *(const bf16x8*)(zl + zo[i] + ko);
      }
    }
    if (kt <= 29) {
      asm volatile("s_waitcnt vmcnt(20)" ::: "memory");  // drains B(t),A(t); keeps A(t+1,t+2),B(t+1)
    } else if (kt == 30) {
      asm volatile("s_waitcnt vmcnt(12)" ::: "memory");
    } else {
      asm volatile("s_waitcnt vmcnt(0)" ::: "memory");
    }
    __builtin_amdgcn_sched_barrier(0);
    __builtin_amdgcn_s_barrier();
    __builtin_amdgcn_sched_barrier(0);
    if (kt <= 29) {  // stage B(t+2) into buf (kt+2)%3 = (kt-1)%3 (read finished, barrier passed)
      const int bnxt = (kt + 2) % 3, ko = (kt + 2) << 5;
#pragma unroll
      for (int q = 0; q < 4; ++q) gld16(&Bt[bnxt][dB + (q << 9)], w1h + bo[q] + ko);
    }
#pragma unroll
    for (int j = 0; j < 4; ++j) {
      bf16x8 bh = *(const bf16x8*)&Bt[cur][swz(wc + (j << 4) + l15, lgp)];
      bf16x8 bl = *(const bf16x8*)&Bt[cur][swz(128 + wc + (j << 4) + l15, lgp)];
#pragma unroll
      for (int i = 0; i < 4; ++i) {
        acc[i][j] = __builtin_amdgcn_mfma_f32_16x16x32_bf16(ah[cur][i], bh, acc[i][j], 0, 0, 0);
        acc[i][j] = __builtin_amdgcn_mfma_f32_16x16x32_bf16(ah[cur][i], bl, acc[i][j], 0, 0, 0);
        acc[i][j] = __builtin_amdgcn_mfma_f32_16x16x32_bf16(al[cur][i], bh, acc[i][j], 0, 0, 0);
      }
    }
  }
  // epilogue: bias + relu, then partial logits over this wave's 64 columns
  float w2r[4][8], b1r[4];
#pragma unroll
  for (int j = 0; j < 4; ++j) {
    int col = bn + wc + (j << 4) + l15;
    float4 p0 = *(const float4*)&w2[(size_t)col * E];
    float4 p1 = *(const float4*)&w2[(size_t)col * E + 4];
    w2r[j][0] = p0.x; w2r[j][1] = p0.y; w2r[j][2] = p0.z; w2r[j][3] = p0.w;
    w2r[j][4] = p1.x; w2r[j][5] = p1.y; w2r[j][6] = p1.z; w2r[j][7] = p1.w;
    b1r[j] = b1eff[col];
  }
#pragma unroll
  for (int i = 0; i < 4; ++i)
#pragma unroll
    for (int j = 0; j < 4; ++j)
#pragma unroll
      for (int r = 0; r < 4; ++r) acc[i][j][r] = fmaxf(acc[i][j][r] + b1r[j], 0.f);
  int wh = wc >> 6;
  size_t pbase = ((size_t)(bnb * 2 + wh) * TT + bm) * E;
#pragma unroll
  for (int e = 0; e < E; ++e) {
    float se[4][4];
#pragma unroll
    for (int i = 0; i < 4; ++i)
#pragma unroll
      for (int r = 0; r < 4; ++r)
        se[i][r] = acc[i][0][r] * w2r[0][e] + acc[i][1][r] * w2r[1][e] +
                   acc[i][2][r] * w2r[2][e] + acc[i][3][r] * w2r[3][e];
#pragma unroll
    for (int off = 1; off < 16; off <<= 1)
#pragma unroll
      for (int i = 0; i < 4; ++i)
#pragma unroll
        for (int r = 0; r < 4; ++r) se[i][r] += __shfl_xor(se[i][r], off);
    if (l15 == 0) {
#pragma unroll
      for (int i = 0; i < 4; ++i)
#pragma unroll
        for (int r = 0; r < 4; ++r) {
          int row = wr + (i << 4) + (lgp << 2) + r;
          plog[pbase + (size_t)row * E + e] = se[i][r];
        }
    }
  }
}

// thread-per-token: sum 16 logit partials + b2 -> softmax -> top2 -> renorm; wave-aggregated lists + psum
__global__ __launch_bounds__(256) void k_top(const float* __restrict__ plog, const float* __restrict__ b2,
                                             int* __restrict__ topE, float* __restrict__ topW,
                                             int* __restrict__ listIdx, float* __restrict__ listW,
                                             int* __restrict__ cnt, double* __restrict__ psum) {
  int t = threadIdx.x, lane = t & 63;
  int tok = (blockIdx.x << 8) + t;
  float lg[E], p[E];
  float4 ba = *reinterpret_cast<const float4*>(b2);
  float4 bb = *reinterpret_cast<const float4*>(b2 + 4);
  lg[0] = ba.x; lg[1] = ba.y; lg[2] = ba.z; lg[3] = ba.w;
  lg[4] = bb.x; lg[5] = bb.y; lg[6] = bb.z; lg[7] = bb.w;
#pragma unroll
  for (int nb = 0; nb < 16; ++nb) {
    const float* pp = &plog[((size_t)nb * TT + tok) * E];
    float4 q0 = *reinterpret_cast<const float4*>(pp);
    float4 q1 = *reinterpret_cast<const float4*>(pp + 4);
    lg[0] += q0.x; lg[1] += q0.y; lg[2] += q0.z; lg[3] += q0.w;
    lg[4] += q1.x; lg[5] += q1.y; lg[6] += q1.z; lg[7] += q1.w;
  }
  float m = lg[0];
#pragma unroll
  for (int e = 1; e < E; ++e) m = fmaxf(m, lg[e]);
  float s = 0.f;
#pragma unroll
  for (int e = 0; e < E; ++e) { p[e] = __expf(lg[e] - m); s += p[e]; }
  float inv = 1.f / s;
#pragma unroll
  for (int e = 0; e < E; ++e) p[e] *= inv;
  {
    float ps[E];
#pragma unroll
    for (int e = 0; e < E; ++e) ps[e] = p[e];
#pragma unroll
    for (int off = 1; off < 64; off <<= 1)
#pragma unroll
      for (int e = 0; e < E; ++e) ps[e] += __shfl_xor(ps[e], off);
    if (lane == 0)
#pragma unroll
      for (int e = 0; e < E; ++e) atomicAdd(&psum[e], (double)ps[e]);
  }
  int e0 = 0;
#pragma unroll
  for (int e = 1; e < E; ++e) if (p[e] > p[e0]) e0 = e;  // strict >: first max (jax tie order)
  int e1 = (e0 == 0) ? 1 : 0;
#pragma unroll
  for (int e = 0; e < E; ++e) if (e != e0 && p[e] > p[e1]) e1 = e;
  float rsw = 1.f / (p[e0] + p[e1]);
  float w0 = p[e0] * rsw, w1v = p[e1] * rsw;
  topE[tok << 1] = e0; topE[(tok << 1) + 1] = e1;
  topW[tok << 1] = w0; topW[(tok << 1) + 1] = w1v;
  unsigned long long lt = (1ull << lane) - 1ull;
#pragma unroll
  for (int e = 0; e < E; ++e) {
    unsigned long long m0 = __ballot(e0 == e);
    unsigned long long m1 = __ballot(e1 == e);
    int n0 = __popcll(m0), total = n0 + __popcll(m1);
    if (total == 0) continue;  // wave-uniform
    int leader = __ffsll(m0 | m1) - 1;
    int base = 0;
    if (lane == leader) base = atomicAdd(&cnt[e], total);
    base = __shfl(base, leader);
    if (e0 == e) {
      int pos = e * TT + base + __popcll(m0 & lt);
      listIdx[pos] = (tok << 1); listW[pos] = w0;
    }
    if (e1 == e) {
      int pos = e * TT + base + n0 + __popcll(m1 & lt);
      listIdx[pos] = (tok << 1) | 1; listW[pos] = w1v;
    }
  }
}

// grouped bf16 MFMA GEMM: gathered token rows @ We[e]^T.
// BM=128, BN=256, BK=32; 4 waves, wave-tile 64x128 (acc 4x8): 32 MFMA / 12KB LDS-read per wave-step.
// A+B via gld16, 3 buffers, counted vmcnt(12) (keeps 2 tiles in flight), 2 barriers/step.
// Grid 2048 (64 bx x 4 by x 8 e), XCD map puts all working blocks first, expert-per-XCD.
__global__ __launch_bounds__(256) void k_expert_gemm(const unsigned short* __restrict__ xb,
                                                     const unsigned short* __restrict__ wet,
                                                     const int* __restrict__ listIdx, const float* __restrict__ listW,
                                                     const int* __restrict__ cnt, unsigned short* __restrict__ ys) {
  int d = blockIdx.x;
  int l = ((d & 7) << 8) + (d >> 3);  // bijective: 2048 blocks, 256/XCD (one expert each)
  int e = l >> 8;
  int lx = l & 255;
  int bx = lx >> 2, by = lx & 3;
  int c = cnt[e];
  int r0 = bx << 7;
  if (r0 >= c) return;
  int n0 = by << 8;  // 256-wide col panel
  __shared__ __align__(16) short A[3][4096];   // 128 rows x 32
  __shared__ __align__(16) short Bs[3][8192];  // 256 rows x 32
  __shared__ int gi[128];
  __shared__ float gw[128];
  int t = threadIdx.x;
  if (t < 128) {
    int rr = r0 + t;
    gi[t] = (rr < c) ? listIdx[e * TT + rr] : -1;
    gw[t] = (rr < c) ? listW[e * TT + rr] : 0.f;
  }
  __syncthreads();
  int w = t >> 6, lane = t & 63;
  int l15 = lane & 15, lgp = lane >> 4;
  int wr = (w >> 1) << 6;   // 0 / 64
  int wc = (w & 1) << 7;    // 0 / 128
  // A staging: 2 slots/thread (s = t, t+256), pre-swizzled gathered sources
  int rA0 = t >> 2, cA0 = (t & 3) ^ ((rA0 >> 1) & 3);
  int sA1 = t + 256;
  int rA1 = sA1 >> 2, cA1 = (sA1 & 3) ^ ((rA1 >> 1) & 3);
  int pk0 = gi[rA0], pk1 = gi[rA1];
  const unsigned short* srcA0 = xb + (size_t)((pk0 < 0) ? 0 : (pk0 >> 1)) * H + (cA0 << 3);
  const unsigned short* srcA1 = xb + (size_t)((pk1 < 0) ? 0 : (pk1 >> 1)) * H + (cA1 << 3);
  // B staging: 4 slots/thread (s = t + q*256)
  int ebase = e << 20;  // e*H*H shorts
  int boB[4];
#pragma unroll
  for (int q = 0; q < 4; ++q) {
    int s = t + (q << 8);
    int r = s >> 2, cg = (s & 3) ^ ((r >> 1) & 3);
    boB[q] = ebase + (n0 + r) * H + (cg << 3);
  }
  int dA = w << 9;  // wave-uniform LDS short offsets
  int dB = w << 9;
  f32x4 acc[4][8];
#pragma unroll
  for (int i = 0; i < 4; ++i)
#pragma unroll
    for (int j = 0; j < 8; ++j) acc[i][j] = f32x4{0.f, 0.f, 0.f, 0.f};
  // prologue: stage tiles 0,1,2 (18 gld16/thread-slot-group, 6 per tile)
#pragma unroll
  for (int pt = 0; pt < 3; ++pt) {
    const int ko = pt << 5;
    gld16(&A[pt][dA], srcA0 + ko);
    gld16(&A[pt][dA + 2048], srcA1 + ko);
#pragma unroll
    for (int q = 0; q < 4; ++q) gld16(&Bs[pt][dB + (q << 11)], wet + boB[q] + ko);
  }
#pragma unroll
  for (int kt = 0; kt < 32; ++kt) {
    if (kt <= 29) {
      asm volatile("s_waitcnt vmcnt(12)" ::: "memory");  // tile kt done; kt+1,kt+2 in flight
    } else if (kt == 30) {
      asm volatile("s_waitcnt vmcnt(6)" ::: "memory");
    } else {
      asm volatile("s_waitcnt vmcnt(0)" ::: "memory");
    }
    __builtin_amdgcn_sched_barrier(0);
    __builtin_amdgcn_s_barrier();
    __builtin_amdgcn_sched_barrier(0);
    const int bb = kt % 3;
    bf16x8 aq[4];
#pragma unroll
    for (int i = 0; i < 4; ++i) aq[i] = *(const bf16x8*)&A[bb][swz(wr + (i << 4) + l15, lgp)];
#pragma unroll
    for (int j = 0; j < 8; ++j) {
      bf16x8 bq = *(const bf16x8*)&Bs[bb][swz(wc + (j << 4) + l15, lgp)];
#pragma unroll
      for (int i = 0; i < 4; ++i)
        acc[i][j] = __builtin_amdgcn_mfma_f32_16x16x32_bf16(aq[i], bq, acc[i][j], 0, 0, 0);
    }
    if (kt <= 28) {  // re-stage buf bb for tile kt+3 (reads done by all waves after barrier)
      __builtin_amdgcn_sched_barrier(0);
      __builtin_amdgcn_s_barrier();
      const int ko = (kt + 3) << 5;
      gld16(&A[bb][dA], srcA0 + ko);
      gld16(&A[bb][dA + 2048], srcA1 + ko);
#pragma unroll
      for (int q = 0; q < 4; ++q) gld16(&Bs[bb][dB + (q << 11)], wet + boB[q] + ko);
    }
  }
#pragma unroll
  for (int i = 0; i < 4; ++i) {
#pragma unroll
    for (int r = 0; r < 4; ++r) {
      int row = wr + (i << 4) + (lgp << 2) + r;  // C/D: col=lane&15, row=(lane>>4)*4+reg
      int pk = gi[row];
      if (pk < 0) continue;
      int tok = pk >> 1, slot = pk & 1;
      float wgt = gw[row];
      size_t ob = ((size_t)slot * TT + tok) * H + n0 + wc + l15;
#pragma unroll
      for (int j = 0; j < 8; ++j) ys[ob + (j << 4)] = __half_as_ushort(__float2half(wgt * acc[i][j][r]));
    }
  }
}

// out = y_slot0 + y_slot1 + w0*be[e0] + w1*be[e1]
__global__ __launch_bounds__(256) void k_combine(const unsigned short* __restrict__ ys, const int* __restrict__ topE,
                                                 const float* __restrict__ topW, const float* __restrict__ be,
                                                 float* __restrict__ out) {
  int tok = blockIdx.x, t = threadIdx.x;
  int e0 = topE[tok << 1], e1 = topE[(tok << 1) + 1];
  float w0 = topW[tok << 1], w1v = topW[(tok << 1) + 1];
  int h = t << 2;
  size_t base = (size_t)tok * H + h;
  ushort4 a = *reinterpret_cast<const ushort4*>(&ys[base]);
  ushort4 b = *reinterpret_cast<const ushort4*>(&ys[(size_t)TT * H + base]);
  float4 b0 = *reinterpret_cast<const float4*>(&be[e0 * H + h]);
  float4 b1v = *reinterpret_cast<const float4*>(&be[e1 * H + h]);
  float4 o;
  o.x = __half2float(__ushort_as_half(a.x)) + __half2float(__ushort_as_half(b.x)) + w0 * b0.x + w1v * b1v.x;
  o.y = __half2float(__ushort_as_half(a.y)) + __half2float(__ushort_as_half(b.y)) + w0 * b0.y + w1v * b1v.y;
  o.z = __half2float(__ushort_as_half(a.z)) + __half2float(__ushort_as_half(b.z)) + w0 * b0.z + w1v * b1v.z;
  o.w = __half2float(__ushort_as_half(a.w)) + __half2float(__ushort_as_half(b.w)) + w0 * b0.w + w1v * b1v.w;
  *reinterpret_cast<float4*>(&out[base]) = o;
}

__global__ __launch_bounds__(64) void k_aux(const double* __restrict__ psum, float* __restrict__ outAux) {
  if (threadIdx.x == 0) {
    double a = 0.0;
    for (int e = 0; e < E; ++e) {
      double mp = psum[e] / (double)TT;
      a += mp * log(mp * (double)E + 1e-9);
    }
    outAux[0] = (float)a;
  }
}

extern "C" void kernel_launch(void* const* d_in, const int* in_sizes, int n_in, void* d_out, int out_size, void* d_ws,
                              size_t ws_size, hipStream_t stream) {
  const float* x = (const float*)d_in[0];
  const float* lsc = (const float*)d_in[1];
  const float* lbi = (const float*)d_in[2];
  const float* w1 = (const float*)d_in[3];
  const float* b1 = (const float*)d_in[4];
  const float* w2 = (const float*)d_in[5];
  const float* b2 = (const float*)d_in[6];
  const float* we = (const float*)d_in[7];
  const float* be = (const float*)d_in[8];
  float* out = (float*)d_out;
  char* ws = (char*)d_ws;

  // ws timeline (peak 66 MB):
  // [0,1M): small; [2,18M): xb; [18,34M): zh -> wet (after router); [34,50M): zl -> ys lo half;
  // [50,54M): w1h+w1l (dead after router); [54,58M): plog (dead after k_top); ys = [34,66M).
  char* p = ws;
  int* topE = (int*)p; p += TT * 2 * 4;
  float* topW = (float*)p; p += TT * 2 * 4;
  int* listIdx = (int*)p; p += E * TT * 4;
  float* listW = (float*)p; p += E * TT * 4;
  int* cnt = (int*)p; p += 256;
  double* psum = (double*)p; p += 2048;
  float* b1eff = (float*)p; p += H * 4;
  float* part = (float*)p; p += 64 * H * 4;
  unsigned short* xb = (unsigned short*)(ws + (2ull << 20));
  unsigned short* zh = (unsigned short*)(ws + (18ull << 20));
  unsigned short* zl = (unsigned short*)(ws + (34ull << 20));
  unsigned short* w1h = (unsigned short*)(ws + (50ull << 20));
  unsigned short* w1l = (unsigned short*)(ws + (52ull << 20));
  float* plog = (float*)(ws + (54ull << 20));
  unsigned short* wet = (unsigned short*)(ws + (18ull << 20));  // overlays zh (after router)
  unsigned short* ys = (unsigned short*)(ws + (34ull << 20));   // overlays zl/w1/plog (after k_top)

  k_init<<<1, 64, 0, stream>>>(cnt, psum);
  k_cast_w1<<<dim3(32, 32), 256, 0, stream>>>(w1, lsc, w1h, w1l);
  k_b1a<<<64, 256, 0, stream>>>(w1, lbi, part);
  k_b1b<<<4, 256, 0, stream>>>(part, b1, b1eff);
  k_stats<<<TT, 256, 0, stream>>>(x, xb, zh, zl);
  k_router_mfma<<<512, 256, 0, stream>>>(zh, zl, w1h, b1eff, w2, plog);
  k_top<<<TT / 256, 256, 0, stream>>>(plog, b2, topE, topW, listIdx, listW, cnt, psum);
  k_cast_we<<<dim3(32, 32, E), 256, 0, stream>>>(we, wet);
  k_expert_gemm<<<2048, 256, 0, stream>>>(xb, wet, listIdx, listW, cnt, ys);
  k_combine<<<TT, 256, 0, stream>>>(ys, topE, topW, be, out);
  k_aux<<<1, 64, 0, stream>>>(psum, out + (size_t)TT * H);
}

// Round 8
// 245.260 us; speedup vs baseline: 1.2873x; 1.0278x over previous
//
#include <hip/hip_runtime.h>
#include <hip/hip_fp16.h>

#define H 1024
#define E 8
#define TT 8192  // tokens = B*S

typedef __attribute__((ext_vector_type(8))) short bf16x8;
typedef __attribute__((ext_vector_type(4))) float f32x4;

__device__ __forceinline__ unsigned short f2bf(float f) {
  unsigned int u = __float_as_uint(f);
  u += 0x7fffu + ((u >> 16) & 1u);
  return (unsigned short)(u >> 16);
}

// LDS tile addressing: rows of 32 bf16 = 64B = 4 chunks of 16B.
// XOR swizzle chunk' = c ^ ((row>>1)&3): conflict-free writes AND mfma b128 reads (0 conflicts, R3-R7).
__device__ __forceinline__ int swz(int row, int c) {
  return (row << 5) | (((c ^ (row >> 1)) & 3) << 3);
}

// async global->LDS, 16B per lane; LDS dest = wave-uniform base + lane*16 (linear).
__device__ __forceinline__ void gld16(void* lds, const void* g) {
  __builtin_amdgcn_global_load_lds((const __attribute__((address_space(1))) void*)g,
                                   (__attribute__((address_space(3))) void*)lds, 16, 0, 0);
}

__global__ __launch_bounds__(64) void k_init(int* cnt, double* psum) {
  int t = threadIdx.x;
  if (t < E) { cnt[t] = 0; psum[t] = 0.0; }
}

// We [E][H][H] f32 -> wet [E][n][k] bf16
__global__ __launch_bounds__(256) void k_cast_we(const float* __restrict__ we, unsigned short* __restrict__ wet) {
  __shared__ unsigned short tile[32][33];
  int e = blockIdx.z;
  int kb = blockIdx.x << 5, nb = blockIdx.y << 5;
  int t = threadIdx.x;
  int cc = t & 31, rr = t >> 5;
  size_t base = (size_t)e * H * H;
#pragma unroll
  for (int r = 0; r < 4; ++r) {
    int k = kb + rr + (r << 3);
    tile[rr + (r << 3)][cc] = f2bf(we[base + (size_t)k * H + nb + cc]);
  }
  __syncthreads();
#pragma unroll
  for (int r = 0; r < 4; ++r) {
    int n = nb + rr + (r << 3);
    wet[base + (size_t)n * H + kb + cc] = tile[cc][rr + (r << 3)];
  }
}

// w1 [k][n] f32 (scaled by lsc[k]) -> w1h/w1l [n][k] bf16 hi/lo split
__global__ __launch_bounds__(256) void k_cast_w1(const float* __restrict__ w1, const float* __restrict__ lsc,
                                                 unsigned short* __restrict__ w1h, unsigned short* __restrict__ w1l) {
  __shared__ float tile[32][33];
  int kb = blockIdx.x << 5, nb = blockIdx.y << 5;
  int t = threadIdx.x;
  int cc = t & 31, rr = t >> 5;
#pragma unroll
  for (int r = 0; r < 4; ++r) {
    int k = kb + rr + (r << 3);
    tile[rr + (r << 3)][cc] = w1[(size_t)k * H + nb + cc] * lsc[k];
  }
  __syncthreads();
#pragma unroll
  for (int r = 0; r < 4; ++r) {
    int n = nb + rr + (r << 3);
    float v = tile[cc][rr + (r << 3)];
    unsigned short h = f2bf(v);
    float hv = __uint_as_float((unsigned)h << 16);
    unsigned short l = f2bf(v - hv);
    w1h[(size_t)n * H + kb + cc] = h;
    w1l[(size_t)n * H + kb + cc] = l;
  }
}

// part[64][H]: block bk sums lbi[k]*w1[k][n] over its 16 k's (deterministic)
__global__ __launch_bounds__(256) void k_b1a(const float* __restrict__ w1, const float* __restrict__ lbi,
                                             float* __restrict__ part) {
  int bk = blockIdx.x, t = threadIdx.x;
  float a0 = 0, a1 = 0, a2 = 0, a3 = 0;
  for (int kk = 0; kk < 16; ++kk) {
    int k = (bk << 4) + kk;
    float lb = lbi[k];
    const float* row = &w1[(size_t)k * H];
    a0 = fmaf(lb, row[t], a0);
    a1 = fmaf(lb, row[t + 256], a1);
    a2 = fmaf(lb, row[t + 512], a2);
    a3 = fmaf(lb, row[t + 768], a3);
  }
  part[bk * H + t] = a0;
  part[bk * H + t + 256] = a1;
  part[bk * H + t + 512] = a2;
  part[bk * H + t + 768] = a3;
}

__global__ __launch_bounds__(256) void k_b1b(const float* __restrict__ part, const float* __restrict__ b1,
                                             float* __restrict__ b1eff) {
  int n = (blockIdx.x << 8) + threadIdx.x;
  float s = b1[n];
  for (int j = 0; j < 64; ++j) s += part[j * H + n];
  b1eff[n] = s;
}

// LN stats + THREE casts: xb = f2bf(x) (experts); zh/zl = trunc hi/lo split of z=(x-m)*rstd (router A).
__global__ __launch_bounds__(256) void k_stats(const float* __restrict__ x, unsigned short* __restrict__ xb,
                                               unsigned short* __restrict__ zh, unsigned short* __restrict__ zl) {
  int tok = blockIdx.x, t = threadIdx.x;
  const float4 v = *reinterpret_cast<const float4*>(&x[(size_t)tok * H + (t << 2)]);
  float s = v.x + v.y + v.z + v.w;
  float ss = v.x * v.x + v.y * v.y + v.z * v.z + v.w * v.w;
#pragma unroll
  for (int off = 32; off; off >>= 1) { s += __shfl_down(s, off); ss += __shfl_down(ss, off); }
  __shared__ float red[4][2];
  int lane = t & 63, wv = t >> 6;
  if (lane == 0) { red[wv][0] = s; red[wv][1] = ss; }
  __syncthreads();
  float fs = red[0][0] + red[1][0] + red[2][0] + red[3][0];
  float fss = red[0][1] + red[1][1] + red[2][1] + red[3][1];
  float mean = fs * (1.0f / H);
  float var = fss * (1.0f / H) - mean * mean;
  float rstd = rsqrtf(var + 1e-5f);
  float mb = -mean * rstd;
  size_t base = (size_t)tok * H + (t << 2);
  ushort4 ob;
  ob.x = f2bf(v.x); ob.y = f2bf(v.y); ob.z = f2bf(v.z); ob.w = f2bf(v.w);
  *reinterpret_cast<ushort4*>(&xb[base]) = ob;
  float zz[4];
  zz[0] = fmaf(v.x, rstd, mb); zz[1] = fmaf(v.y, rstd, mb);
  zz[2] = fmaf(v.z, rstd, mb); zz[3] = fmaf(v.w, rstd, mb);
  ushort4 oh, ol;
  unsigned u0 = __float_as_uint(zz[0]), u1 = __float_as_uint(zz[1]);
  unsigned u2 = __float_as_uint(zz[2]), u3 = __float_as_uint(zz[3]);
  oh.x = (unsigned short)(u0 >> 16); oh.y = (unsigned short)(u1 >> 16);
  oh.z = (unsigned short)(u2 >> 16); oh.w = (unsigned short)(u3 >> 16);
  float l0 = zz[0] - __uint_as_float(u0 & 0xffff0000u);
  float l1 = zz[1] - __uint_as_float(u1 & 0xffff0000u);
  float l2 = zz[2] - __uint_as_float(u2 & 0xffff0000u);
  float l3 = zz[3] - __uint_as_float(u3 & 0xffff0000u);
  ol.x = (unsigned short)(__float_as_uint(l0) >> 16); ol.y = (unsigned short)(__float_as_uint(l1) >> 16);
  ol.z = (unsigned short)(__float_as_uint(l2) >> 16); ol.w = (unsigned short)(__float_as_uint(l3) >> 16);
  *reinterpret_cast<ushort4*>(&zh[base]) = oh;
  *reinterpret_cast<ushort4*>(&zl[base]) = ol;
}

// Router GEMM: hmid-tile = z @ (lsc*w1), 3-pass hi/lo bf16 MFMA. (unchanged from R7)
__global__ __launch_bounds__(256) void k_router_mfma(
    const unsigned short* __restrict__ zh, const unsigned short* __restrict__ zl,
    const unsigned short* __restrict__ w1h,  // w1l = w1h + 1048576 shorts (adjacent in ws)
    const float* __restrict__ b1eff, const float* __restrict__ w2, float* __restrict__ plog) {
  __shared__ __align__(16) short Bt[3][8192];  // 3 x (256 rows x 32): rows 0-127 hi, 128-255 lo
  int t = threadIdx.x;
  int d = blockIdx.x;
  int l = ((d & 7) << 6) + (d >> 3);  // XCD owns contiguous 64-block chunk (bijective, 512 blocks)
  int bm = (l >> 3) << 7;
  int bnb = l & 7, bn = bnb << 7;
  int w = t >> 6, lane = t & 63;
  int l15 = lane & 15, lgp = lane >> 4;
  int wr = (w >> 1) << 6, wc = (w & 1) << 6;
  int sl = (w << 8) + lane;
  int bo[4];
#pragma unroll
  for (int q = 0; q < 4; ++q) {
    int s = sl + (q << 6);
    int r = s >> 2, cg = (s & 3) ^ ((r >> 1) & 3);
    bo[q] = ((r < 128) ? (bn + r) * H : 1048576 + (bn + r - 128) * H) + (cg << 3);
  }
  int dB = w << 11;
  int zo[4];
#pragma unroll
  for (int i = 0; i < 4; ++i) zo[i] = (bm + wr + (i << 4) + l15) * H + (lgp << 3);
  f32x4 acc[4][4];
#pragma unroll
  for (int i = 0; i < 4; ++i)
#pragma unroll
    for (int j = 0; j < 4; ++j) acc[i][j] = f32x4{0.f, 0.f, 0.f, 0.f};
  bf16x8 ah[3][4], al[3][4];
#pragma unroll
  for (int q = 0; q < 4; ++q) gld16(&Bt[0][dB + (q << 9)], w1h + bo[q]);
#pragma unroll
  for (int q = 0; q < 4; ++q) gld16(&Bt[1][dB + (q << 9)], w1h + bo[q] + 32);
#pragma unroll
  for (int i = 0; i < 4; ++i) {
    ah[0][i] = *(const bf16x8*)(zh + zo[i]);
    al[0][i] = *(const bf16x8*)(zl + zo[i]);
    ah[1][i] = *(const bf16x8*)(zh + zo[i] + 32);
    al[1][i] = *(const bf16x8*)(zl + zo[i] + 32);
  }
#pragma unroll
  for (int kt = 0; kt < 32; ++kt) {
    const int cur = kt % 3;
    if (kt <= 29) {
      const int slot = (kt + 2) % 3, ko = (kt + 2) << 5;
#pragma unroll
      for (int i = 0; i < 4; ++i) {
        ah[slot][i] = *(const bf16x8*)(zh + zo[i] + ko);
        al[slot][i] = *(const bf16x8*)(zl + zo[i] + ko);
      }
    }
    if (kt <= 29) {
      asm volatile("s_waitcnt vmcnt(20)" ::: "memory");
    } else if (kt == 30) {
      asm volatile("s_waitcnt vmcnt(12)" ::: "memory");
    } else {
      asm volatile("s_waitcnt vmcnt(0)" ::: "memory");
    }
    __builtin_amdgcn_sched_barrier(0);
    __builtin_amdgcn_s_barrier();
    __builtin_amdgcn_sched_barrier(0);
    if (kt <= 29) {
      const int bnxt = (kt + 2) % 3, ko = (kt + 2) << 5;
#pragma unroll
      for (int q = 0; q < 4; ++q) gld16(&Bt[bnxt][dB + (q << 9)], w1h + bo[q] + ko);
    }
#pragma unroll
    for (int j = 0; j < 4; ++j) {
      bf16x8 bh = *(const bf16x8*)&Bt[cur][swz(wc + (j << 4) + l15, lgp)];
      bf16x8 bl = *(const bf16x8*)&Bt[cur][swz(128 + wc + (j << 4) + l15, lgp)];
#pragma unroll
      for (int i = 0; i < 4; ++i) {
        acc[i][j] = __builtin_amdgcn_mfma_f32_16x16x32_bf16(ah[cur][i], bh, acc[i][j], 0, 0, 0);
        acc[i][j] = __builtin_amdgcn_mfma_f32_16x16x32_bf16(ah[cur][i], bl, acc[i][j], 0, 0, 0);
        acc[i][j] = __builtin_amdgcn_mfma_f32_16x16x32_bf16(al[cur][i], bh, acc[i][j], 0, 0, 0);
      }
    }
  }
  float w2r[4][8], b1r[4];
#pragma unroll
  for (int j = 0; j < 4; ++j) {
    int col = bn + wc + (j << 4) + l15;
    float4 p0 = *(const float4*)&w2[(size_t)col * E];
    float4 p1 = *(const float4*)&w2[(size_t)col * E + 4];
    w2r[j][0] = p0.x; w2r[j][1] = p0.y; w2r[j][2] = p0.z; w2r[j][3] = p0.w;
    w2r[j][4] = p1.x; w2r[j][5] = p1.y; w2r[j][6] = p1.z; w2r[j][7] = p1.w;
    b1r[j] = b1eff[col];
  }
#pragma unroll
  for (int i = 0; i < 4; ++i)
#pragma unroll
    for (int j = 0; j < 4; ++j)
#pragma unroll
      for (int r = 0; r < 4; ++r) acc[i][j][r] = fmaxf(acc[i][j][r] + b1r[j], 0.f);
  int wh = wc >> 6;
  size_t pbase = ((size_t)(bnb * 2 + wh) * TT + bm) * E;
#pragma unroll
  for (int e = 0; e < E; ++e) {
    float se[4][4];
#pragma unroll
    for (int i = 0; i < 4; ++i)
#pragma unroll
      for (int r = 0; r < 4; ++r)
        se[i][r] = acc[i][0][r] * w2r[0][e] + acc[i][1][r] * w2r[1][e] +
                   acc[i][2][r] * w2r[2][e] + acc[i][3][r] * w2r[3][e];
#pragma unroll
    for (int off = 1; off < 16; off <<= 1)
#pragma unroll
      for (int i = 0; i < 4; ++i)
#pragma unroll
        for (int r = 0; r < 4; ++r) se[i][r] += __shfl_xor(se[i][r], off);
    if (l15 == 0) {
#pragma unroll
      for (int i = 0; i < 4; ++i)
#pragma unroll
        for (int r = 0; r < 4; ++r) {
          int row = wr + (i << 4) + (lgp << 2) + r;
          plog[pbase + (size_t)row * E + e] = se[i][r];
        }
    }
  }
}

// thread-per-token: sum 16 logit partials + b2 -> softmax -> top2 -> renorm; wave-aggregated lists + psum
__global__ __launch_bounds__(256) void k_top(const float* __restrict__ plog, const float* __restrict__ b2,
                                             int* __restrict__ topE, float* __restrict__ topW,
                                             int* __restrict__ listIdx, float* __restrict__ listW,
                                             int* __restrict__ cnt, double* __restrict__ psum) {
  int t = threadIdx.x, lane = t & 63;
  int tok = (blockIdx.x << 8) + t;
  float lg[E], p[E];
  float4 ba = *reinterpret_cast<const float4*>(b2);
  float4 bb = *reinterpret_cast<const float4*>(b2 + 4);
  lg[0] = ba.x; lg[1] = ba.y; lg[2] = ba.z; lg[3] = ba.w;
  lg[4] = bb.x; lg[5] = bb.y; lg[6] = bb.z; lg[7] = bb.w;
#pragma unroll
  for (int nb = 0; nb < 16; ++nb) {
    const float* pp = &plog[((size_t)nb * TT + tok) * E];
    float4 q0 = *reinterpret_cast<const float4*>(pp);
    float4 q1 = *reinterpret_cast<const float4*>(pp + 4);
    lg[0] += q0.x; lg[1] += q0.y; lg[2] += q0.z; lg[3] += q0.w;
    lg[4] += q1.x; lg[5] += q1.y; lg[6] += q1.z; lg[7] += q1.w;
  }
  float m = lg[0];
#pragma unroll
  for (int e = 1; e < E; ++e) m = fmaxf(m, lg[e]);
  float s = 0.f;
#pragma unroll
  for (int e = 0; e < E; ++e) { p[e] = __expf(lg[e] - m); s += p[e]; }
  float inv = 1.f / s;
#pragma unroll
  for (int e = 0; e < E; ++e) p[e] *= inv;
  {
    float ps[E];
#pragma unroll
    for (int e = 0; e < E; ++e) ps[e] = p[e];
#pragma unroll
    for (int off = 1; off < 64; off <<= 1)
#pragma unroll
      for (int e = 0; e < E; ++e) ps[e] += __shfl_xor(ps[e], off);
    if (lane == 0)
#pragma unroll
      for (int e = 0; e < E; ++e) atomicAdd(&psum[e], (double)ps[e]);
  }
  int e0 = 0;
#pragma unroll
  for (int e = 1; e < E; ++e) if (p[e] > p[e0]) e0 = e;  // strict >: first max (jax tie order)
  int e1 = (e0 == 0) ? 1 : 0;
#pragma unroll
  for (int e = 0; e < E; ++e) if (e != e0 && p[e] > p[e1]) e1 = e;
  float rsw = 1.f / (p[e0] + p[e1]);
  float w0 = p[e0] * rsw, w1v = p[e1] * rsw;
  topE[tok << 1] = e0; topE[(tok << 1) + 1] = e1;
  topW[tok << 1] = w0; topW[(tok << 1) + 1] = w1v;
  unsigned long long lt = (1ull << lane) - 1ull;
#pragma unroll
  for (int e = 0; e < E; ++e) {
    unsigned long long m0 = __ballot(e0 == e);
    unsigned long long m1 = __ballot(e1 == e);
    int n0 = __popcll(m0), total = n0 + __popcll(m1);
    if (total == 0) continue;  // wave-uniform
    int leader = __ffsll(m0 | m1) - 1;
    int base = 0;
    if (lane == leader) base = atomicAdd(&cnt[e], total);
    base = __shfl(base, leader);
    if (e0 == e) {
      int pos = e * TT + base + __popcll(m0 & lt);
      listIdx[pos] = (tok << 1); listW[pos] = w0;
    }
    if (e1 == e) {
      int pos = e * TT + base + n0 + __popcll(m1 & lt);
      listIdx[pos] = (tok << 1) | 1; listW[pos] = w1v;
    }
  }
}

// Build exact work list: item (e,bx,by) at slot g*8+e (XCD k <- expert k). ~1024 items; rest -1.
#define WL_SLOTS 2560
__global__ __launch_bounds__(256) void k_sched(const int* __restrict__ cnt, int* __restrict__ workList) {
  int t = threadIdx.x;
  for (int i = t; i < WL_SLOTS; i += 256) workList[i] = -1;
  __syncthreads();
  if (t < E) {
    int e = t;
    int nb = (cnt[e] + 127) >> 7;
    int ov = 2048 + (e << 6);  // per-expert overflow region (64 slots; unreachable for balanced data)
    int g = 0;
    for (int bx = 0; bx < nb; ++bx) {
      for (int by = 0; by < 8; ++by) {
        int item = (e << 12) | (bx << 4) | by;
        int slot = (g < 256) ? ((g << 3) + e) : ov++;
        workList[slot] = item;
        ++g;
      }
    }
  }
}

// grouped bf16 MFMA GEMM via exact work list: gathered token rows @ We[e]^T.
// BM=128, BN=128, BK=32; 4 waves 2x2; A+B gld16 2-buffer (33 KB -> 4 blocks/CU); counted vmcnt(4);
// 2 barriers/step; setprio around MFMA cluster.
__global__ __launch_bounds__(256) void k_expert_gemm(const unsigned short* __restrict__ xb,
                                                     const unsigned short* __restrict__ wet,
                                                     const int* __restrict__ listIdx, const float* __restrict__ listW,
                                                     const int* __restrict__ cnt, const int* __restrict__ workList,
                                                     unsigned short* __restrict__ ys) {
  int item = workList[blockIdx.x];
  if (item < 0) return;
  int e = item >> 12, bx = (item >> 4) & 255, by = item & 15;
  int c = cnt[e];
  int r0 = bx << 7, n0 = by << 7;
  __shared__ __align__(16) short A[2][4096], Bs[2][4096];
  __shared__ int gi[128];
  __shared__ float gw[128];
  int t = threadIdx.x;
  if (t < 128) {
    int rr = r0 + t;
    gi[t] = (rr < c) ? listIdx[e * TT + rr] : -1;
    gw[t] = (rr < c) ? listW[e * TT + rr] : 0.f;
  }
  __syncthreads();
  int w = t >> 6, lane = t & 63;
  int l15 = lane & 15, lgp = lane >> 4;
  int wr = (w >> 1) << 6, wc = (w & 1) << 6;
  // staging: 2 slots/thread per operand, pre-swizzled global chunk
  int s0 = (w << 7) + lane, s1 = s0 + 64;
  int rA0 = s0 >> 2, cg0 = (s0 & 3) ^ ((rA0 >> 1) & 3);
  int rA1 = s1 >> 2, cg1 = (s1 & 3) ^ ((rA1 >> 1) & 3);
  int pk0 = gi[rA0], pk1 = gi[rA1];
  const unsigned short* srcA0 = xb + (size_t)((pk0 < 0) ? 0 : (pk0 >> 1)) * H + (cg0 << 3);
  const unsigned short* srcA1 = xb + (size_t)((pk1 < 0) ? 0 : (pk1 >> 1)) * H + (cg1 << 3);
  size_t wbase = (size_t)e * H * H;
  const unsigned short* srcB0 = wet + wbase + (size_t)(n0 + rA0) * H + (cg0 << 3);
  const unsigned short* srcB1 = wet + wbase + (size_t)(n0 + rA1) * H + (cg1 << 3);
  int d0 = (w << 10), d1 = d0 + 512;  // wave-uniform LDS short offsets
  f32x4 acc[4][4];
#pragma unroll
  for (int i = 0; i < 4; ++i)
#pragma unroll
    for (int j = 0; j < 4; ++j) acc[i][j] = f32x4{0.f, 0.f, 0.f, 0.f};
  // prologue: stage tile 0
  gld16(&A[0][d0], srcA0); gld16(&A[0][d1], srcA1);
  gld16(&Bs[0][d0], srcB0); gld16(&Bs[0][d1], srcB1);
#pragma unroll
  for (int kt = 0; kt < 32; ++kt) {
    const int cur = kt & 1, nxt = cur ^ 1;
    if (kt < 31) {  // issue next tile first; its 4 loads stay in flight across the wait
      const int ko = (kt + 1) << 5;
      gld16(&A[nxt][d0], srcA0 + ko); gld16(&A[nxt][d1], srcA1 + ko);
      gld16(&Bs[nxt][d0], srcB0 + ko); gld16(&Bs[nxt][d1], srcB1 + ko);
      asm volatile("s_waitcnt vmcnt(4)" ::: "memory");  // tile kt landed; kt+1 in flight
    } else {
      asm volatile("s_waitcnt vmcnt(0)" ::: "memory");
    }
    __builtin_amdgcn_sched_barrier(0);
    __builtin_amdgcn_s_barrier();
    __builtin_amdgcn_sched_barrier(0);
    bf16x8 bq[4];
#pragma unroll
    for (int j = 0; j < 4; ++j) bq[j] = *(const bf16x8*)&Bs[cur][swz(wc + (j << 4) + l15, lgp)];
    bf16x8 aq[4];
#pragma unroll
    for (int i = 0; i < 4; ++i) aq[i] = *(const bf16x8*)&A[cur][swz(wr + (i << 4) + l15, lgp)];
    __builtin_amdgcn_s_setprio(1);
#pragma unroll
    for (int i = 0; i < 4; ++i)
#pragma unroll
      for (int j = 0; j < 4; ++j)
        acc[i][j] = __builtin_amdgcn_mfma_f32_16x16x32_bf16(aq[i], bq[j], acc[i][j], 0, 0, 0);
    __builtin_amdgcn_s_setprio(0);
    if (kt < 31) {  // end-of-step: all waves done reading buf cur -> next step may restage it
      __builtin_amdgcn_sched_barrier(0);
      __builtin_amdgcn_s_barrier();
    }
  }
#pragma unroll
  for (int i = 0; i < 4; ++i) {
#pragma unroll
    for (int r = 0; r < 4; ++r) {
      int row = wr + (i << 4) + (lgp << 2) + r;  // C/D: col=lane&15, row=(lane>>4)*4+reg
      int pk = gi[row];
      if (pk < 0) continue;
      int tok = pk >> 1, slot = pk & 1;
      float wgt = gw[row];
      size_t ob = ((size_t)slot * TT + tok) * H + n0 + wc + l15;
#pragma unroll
      for (int j = 0; j < 4; ++j) ys[ob + (j << 4)] = __half_as_ushort(__float2half(wgt * acc[i][j][r]));
    }
  }
}

// out = y_slot0 + y_slot1 + w0*be[e0] + w1*be[e1]
__global__ __launch_bounds__(256) void k_combine(const unsigned short* __restrict__ ys, const int* __restrict__ topE,
                                                 const float* __restrict__ topW, const float* __restrict__ be,
                                                 float* __restrict__ out) {
  int tok = blockIdx.x, t = threadIdx.x;
  int e0 = topE[tok << 1], e1 = topE[(tok << 1) + 1];
  float w0 = topW[tok << 1], w1v = topW[(tok << 1) + 1];
  int h = t << 2;
  size_t base = (size_t)tok * H + h;
  ushort4 a = *reinterpret_cast<const ushort4*>(&ys[base]);
  ushort4 b = *reinterpret_cast<const ushort4*>(&ys[(size_t)TT * H + base]);
  float4 b0 = *reinterpret_cast<const float4*>(&be[e0 * H + h]);
  float4 b1v = *reinterpret_cast<const float4*>(&be[e1 * H + h]);
  float4 o;
  o.x = __half2float(__ushort_as_half(a.x)) + __half2float(__ushort_as_half(b.x)) + w0 * b0.x + w1v * b1v.x;
  o.y = __half2float(__ushort_as_half(a.y)) + __half2float(__ushort_as_half(b.y)) + w0 * b0.y + w1v * b1v.y;
  o.z = __half2float(__ushort_as_half(a.z)) + __half2float(__ushort_as_half(b.z)) + w0 * b0.z + w1v * b1v.z;
  o.w = __half2float(__ushort_as_half(a.w)) + __half2float(__ushort_as_half(b.w)) + w0 * b0.w + w1v * b1v.w;
  *reinterpret_cast<float4*>(&out[base]) = o;
}

__global__ __launch_bounds__(64) void k_aux(const double* __restrict__ psum, float* __restrict__ outAux) {
  if (threadIdx.x == 0) {
    double a = 0.0;
    for (int e = 0; e < E; ++e) {
      double mp = psum[e] / (double)TT;
      a += mp * log(mp * (double)E + 1e-9);
    }
    outAux[0] = (float)a;
  }
}

extern "C" void kernel_launch(void* const* d_in, const int* in_sizes, int n_in, void* d_out, int out_size, void* d_ws,
                              size_t ws_size, hipStream_t stream) {
  const float* x = (const float*)d_in[0];
  const float* lsc = (const float*)d_in[1];
  const float* lbi = (const float*)d_in[2];
  const float* w1 = (const float*)d_in[3];
  const float* b1 = (const float*)d_in[4];
  const float* w2 = (const float*)d_in[5];
  const float* b2 = (const float*)d_in[6];
  const float* we = (const float*)d_in[7];
  const float* be = (const float*)d_in[8];
  float* out = (float*)d_out;
  char* ws = (char*)d_ws;

  // ws timeline (peak 66 MB):
  // [0,2M): small; [2,18M): xb; [18,34M): zh -> wet (after router); [34,50M): zl -> ys lo half;
  // [50,54M): w1h+w1l (dead after router); [54,58M): plog (dead after k_top); ys = [34,66M).
  char* p = ws;
  int* topE = (int*)p; p += TT * 2 * 4;
  float* topW = (float*)p; p += TT * 2 * 4;
  int* listIdx = (int*)p; p += E * TT * 4;
  float* listW = (float*)p; p += E * TT * 4;
  int* cnt = (int*)p; p += 256;
  double* psum = (double*)p; p += 2048;
  float* b1eff = (float*)p; p += H * 4;
  float* part = (float*)p; p += 64 * H * 4;
  int* workList = (int*)p; p += WL_SLOTS * 4;
  unsigned short* xb = (unsigned short*)(ws + (2ull << 20));
  unsigned short* zh = (unsigned short*)(ws + (18ull << 20));
  unsigned short* zl = (unsigned short*)(ws + (34ull << 20));
  unsigned short* w1h = (unsigned short*)(ws + (50ull << 20));
  unsigned short* w1l = (unsigned short*)(ws + (52ull << 20));
  float* plog = (float*)(ws + (54ull << 20));
  unsigned short* wet = (unsigned short*)(ws + (18ull << 20));  // overlays zh (after router)
  unsigned short* ys = (unsigned short*)(ws + (34ull << 20));   // overlays zl/w1/plog (after k_top)

  k_init<<<1, 64, 0, stream>>>(cnt, psum);
  k_cast_w1<<<dim3(32, 32), 256, 0, stream>>>(w1, lsc, w1h, w1l);
  k_b1a<<<64, 256, 0, stream>>>(w1, lbi, part);
  k_b1b<<<4, 256, 0, stream>>>(part, b1, b1eff);
  k_stats<<<TT, 256, 0, stream>>>(x, xb, zh, zl);
  k_router_mfma<<<512, 256, 0, stream>>>(zh, zl, w1h, b1eff, w2, plog);
  k_top<<<TT / 256, 256, 0, stream>>>(plog, b2, topE, topW, listIdx, listW, cnt, psum);
  k_sched<<<1, 256, 0, stream>>>(cnt, workList);
  k_cast_we<<<dim3(32, 32, E), 256, 0, stream>>>(we, wet);
  k_expert_gemm<<<WL_SLOTS, 256, 0, stream>>>(xb, wet, listIdx, listW, cnt, workList, ys);
  k_combine<<<TT, 256, 0, stream>>>(ys, topE, topW, be, out);
  k_aux<<<1, 64, 0, stream>>>(psum, out + (size_t)TT * H);
}